// Round 1
// baseline (2166.031 us; speedup 1.0000x reference)
//
#include <hip/hip_runtime.h>
#include <hip/hip_bf16.h>

typedef __attribute__((ext_vector_type(4))) float  floatx4;
typedef __attribute__((ext_vector_type(8))) short  shortx8;
typedef __attribute__((ext_vector_type(4))) short  shortx4;

__device__ __forceinline__ short f2bf(float x) {
    union { float f; unsigned u; } v; v.f = x;
    unsigned r = v.u + 0x7FFFu + ((v.u >> 16) & 1u);   // round-to-nearest-even
    return (short)(r >> 16);
}

// ---------------- prep kernels ----------------

__global__ void cast_bf16(const float* __restrict__ src, short* __restrict__ dst, int n4) {
    int i = blockIdx.x * blockDim.x + threadIdx.x;
    if (i < n4) {
        floatx4 v = ((const floatx4*)src)[i];
        shortx4 s;
        s[0] = f2bf(v[0]); s[1] = f2bf(v[1]); s[2] = f2bf(v[2]); s[3] = f2bf(v[3]);
        ((shortx4*)dst)[i] = s;
    }
}

// dst[c][r] = (bf16)src[r][c], per-z batch. src: R x C fp32. dst: C x R bf16.
__global__ void transpose_cast(const float* __restrict__ src, short* __restrict__ dst,
                               int R, int C, long szSrc, long szDst) {
    __shared__ float tile[32][33];
    const float* s = src + (long)blockIdx.z * szSrc;
    short* d = dst + (long)blockIdx.z * szDst;
    int c0 = blockIdx.x * 32, r0 = blockIdx.y * 32;
    for (int i = threadIdx.y; i < 32; i += 8)
        tile[i][threadIdx.x] = s[(long)(r0 + i) * C + c0 + threadIdx.x];
    __syncthreads();
    for (int i = threadIdx.y; i < 32; i += 8)
        d[(long)(c0 + i) * R + r0 + threadIdx.x] = f2bf(tile[threadIdx.x][i]);
}

// ---------------- NT GEMM: C[M,N] = A[M,K] * B[N,K]^T ----------------
// 128x128 tile, BK=32, 256 threads = 4 waves (2x2), each wave 4x4 mfma 16x16x32.
// A source fp32 (convert on stage) when AF32, else bf16. B always bf16.
// aHX: extra element offset added per 4096 of k (for per-head attn layout).

#define BM 128
#define BN 128
#define BK 32

template<bool AF32, bool RELU, bool CF32>
__global__ __launch_bounds__(256) void gemm_nt(
    const void* __restrict__ Ap, const short* __restrict__ Bp, void* __restrict__ Cp,
    const float* __restrict__ bias, float alpha,
    int K, int lda, int ldb, int ldc,
    long sAz, long sBz, long sCz, long aHX)
{
    __shared__ __align__(16) short As[BM * BK];
    __shared__ __align__(16) short Bs[BN * BK];

    const int t    = threadIdx.x;
    const int m0   = blockIdx.y * BM;
    const int n0   = blockIdx.x * BN;
    const int z    = blockIdx.z;
    const int wave = t >> 6, lane = t & 63;
    const int wm   = (wave & 1) * 64, wn = (wave >> 1) * 64;
    const int quad = lane >> 4, l16 = lane & 15;

    const short* Bz = Bp + (long)z * sBz;

    floatx4 acc[4][4] = {};

    for (int k0 = 0; k0 < K; k0 += BK) {
        const long hoff = (long)(k0 >> 12) * aHX;
        __syncthreads();
        if (AF32) {
            const float* Az = (const float*)Ap + (long)z * sAz + hoff;
            #pragma unroll
            for (int p = 0; p < 4; ++p) {
                int idx = (p * 256 + t) * 4;
                int row = idx >> 5, kk = idx & 31;
                floatx4 v = *(const floatx4*)(Az + (long)(m0 + row) * lda + (k0 + kk));
                shortx4 sv;
                sv[0] = f2bf(v[0]); sv[1] = f2bf(v[1]); sv[2] = f2bf(v[2]); sv[3] = f2bf(v[3]);
                *(shortx4*)(&As[row * BK + kk]) = sv;
            }
        } else {
            const short* Az = (const short*)Ap + (long)z * sAz + hoff;
            #pragma unroll
            for (int p = 0; p < 2; ++p) {
                int idx = (p * 256 + t) * 8;
                int row = idx >> 5, kk = idx & 31;
                *(shortx8*)(&As[row * BK + kk]) =
                    *(const shortx8*)(Az + (long)(m0 + row) * lda + (k0 + kk));
            }
        }
        #pragma unroll
        for (int p = 0; p < 2; ++p) {
            int idx = (p * 256 + t) * 8;
            int row = idx >> 5, kk = idx & 31;
            *(shortx8*)(&Bs[row * BK + kk]) =
                *(const shortx8*)(Bz + (long)(n0 + row) * ldb + (k0 + kk));
        }
        __syncthreads();

        shortx8 af[4], bfr[4];
        #pragma unroll
        for (int i = 0; i < 4; ++i)
            af[i] = *(const shortx8*)(&As[(wm + i * 16 + l16) * BK + quad * 8]);
        #pragma unroll
        for (int j = 0; j < 4; ++j)
            bfr[j] = *(const shortx8*)(&Bs[(wn + j * 16 + l16) * BK + quad * 8]);
        #pragma unroll
        for (int i = 0; i < 4; ++i)
            #pragma unroll
            for (int j = 0; j < 4; ++j)
                acc[i][j] = __builtin_amdgcn_mfma_f32_16x16x32_bf16(af[i], bfr[j], acc[i][j], 0, 0, 0);
    }

    // epilogue: C/D layout col=lane&15, row=quad*4+e (m89-verified)
    float bv[4];
    #pragma unroll
    for (int j = 0; j < 4; ++j)
        bv[j] = bias ? bias[n0 + wn + j * 16 + l16] : 0.0f;

    #pragma unroll
    for (int i = 0; i < 4; ++i) {
        #pragma unroll
        for (int e = 0; e < 4; ++e) {
            long row = m0 + wm + i * 16 + quad * 4 + e;
            #pragma unroll
            for (int j = 0; j < 4; ++j) {
                float val = acc[i][j][e] * alpha + bv[j];
                if (RELU) val = fmaxf(val, 0.0f);
                long col = n0 + wn + j * 16 + l16;
                if (CF32) ((float*)Cp + (long)z * sCz)[row * ldc + col] = val;
                else      ((short*)Cp + (long)z * sCz)[row * ldc + col] = f2bf(val);
            }
        }
    }
}

// ---------------- softmax(row) * mask, in place on fp32 scores ----------------

__global__ __launch_bounds__(256) void softmax_mask(float* __restrict__ attn,
                                                    const float* __restrict__ mask) {
    float* p = attn + (long)blockIdx.x * 4096;
    const int t = threadIdx.x;
    float v[16];
    float mx = -3.4e38f;
    #pragma unroll
    for (int i = 0; i < 16; ++i) { v[i] = p[t + 256 * i]; mx = fmaxf(mx, v[i]); }
    #pragma unroll
    for (int o = 32; o > 0; o >>= 1) mx = fmaxf(mx, __shfl_down(mx, o));
    __shared__ float r1[4], r2[4];
    const int lane = t & 63, w = t >> 6;
    if (lane == 0) r1[w] = mx;
    __syncthreads();
    mx = fmaxf(fmaxf(r1[0], r1[1]), fmaxf(r1[2], r1[3]));
    float s = 0.f;
    #pragma unroll
    for (int i = 0; i < 16; ++i) { v[i] = __expf(v[i] - mx); s += v[i]; }
    #pragma unroll
    for (int o = 32; o > 0; o >>= 1) s += __shfl_down(s, o);
    if (lane == 0) r2[w] = s;
    __syncthreads();
    s = r2[0] + r2[1] + r2[2] + r2[3];
    const float inv = 1.0f / s;
    #pragma unroll
    for (int i = 0; i < 16; ++i) p[t + 256 * i] = v[i] * inv * mask[t + 256 * i];
}

// ---------------- launch ----------------

extern "C" void kernel_launch(void* const* d_in, const int* in_sizes, int n_in,
                              void* d_out, int out_size, void* d_ws, size_t ws_size,
                              hipStream_t stream) {
    const float* sentences = (const float*)d_in[0];
    const float* knowledge = (const float*)d_in[1];
    const float* mask      = (const float*)d_in[2];
    const float* Ws        = (const float*)d_in[3];
    const float* bs        = (const float*)d_in[4];
    const float* Wk        = (const float*)d_in[5];
    const float* bk        = (const float*)d_in[6];
    const float* W1        = (const float*)d_in[7];
    const float* b1        = (const float*)d_in[8];
    const float* W2        = (const float*)d_in[9];
    const float* b2        = (const float*)d_in[10];

    float* out  = (float*)d_out;
    float* attn = out + 4194304;           // weights region: [8*4096, 4096] fp32

    char* ws = (char*)d_ws;
    short* sent_bf = (short*)(ws);                  //  8 MB
    short* know_bf = (short*)(ws + 8388608);        //  8 MB
    short* WsT     = (short*)(ws + 16777216);       //  2 MB  [j=h*128+e][d]
    short* WkT     = (short*)(ws + 18874368);       //  2 MB
    short* W1T     = (short*)(ws + 20971520);       // 16 MB  [h][j][d]
    short* W2T     = (short*)(ws + 37748736);       //  2 MB  [j2][j]
    short* S_bf    = (short*)(ws + 39845888);       //  8 MB  [n][h*128+e]
    short* K_bf    = (short*)(ws + 48234496);       //  8 MB  [m][h*128+e]
    short* V_T     = (short*)(ws + 56623104);       // 64 MB  [j][h*4096+m]
    short* h_bf    = (short*)(ws + 123731968);      //  8 MB  [n][j]

    // prep: casts + weight transposes
    cast_bf16<<<4096, 256, 0, stream>>>(sentences, sent_bf, 1048576);
    cast_bf16<<<4096, 256, 0, stream>>>(knowledge, know_bf, 1048576);
    transpose_cast<<<dim3(4, 32, 8),  dim3(32, 8), 0, stream>>>(Ws, WsT, 1024, 128, 131072, 131072);
    transpose_cast<<<dim3(4, 32, 8),  dim3(32, 8), 0, stream>>>(Wk, WkT, 1024, 128, 131072, 131072);
    transpose_cast<<<dim3(32, 32, 8), dim3(32, 8), 0, stream>>>(W1, W1T, 1024, 1024, 1048576, 1048576);
    transpose_cast<<<dim3(32, 32, 1), dim3(32, 8), 0, stream>>>(W2, W2T, 1024, 1024, 0, 0);

    // S = sentences @ Ws + bs   -> S_bf [4096,1024]
    gemm_nt<false, false, false><<<dim3(8, 32, 1), 256, 0, stream>>>(
        sent_bf, WsT, S_bf, bs, 1.0f, 1024, 1024, 1024, 1024, 0, 0, 0, 0);
    // K = knowledge @ Wk + bk   -> K_bf [4096,1024]
    gemm_nt<false, false, false><<<dim3(8, 32, 1), 256, 0, stream>>>(
        know_bf, WkT, K_bf, bk, 1.0f, 1024, 1024, 1024, 1024, 0, 0, 0, 0);
    // V_T[j][h*4096+m] = (knowledge @ W1_h)[m][j]
    gemm_nt<false, false, false><<<dim3(32, 8, 8), 256, 0, stream>>>(
        W1T, know_bf, V_T, nullptr, 1.0f, 1024, 1024, 1024, 32768, 1048576, 0, 4096, 0);
    // raw scores -> d_out weights region (fp32), scaled 1/sqrt(128)
    gemm_nt<false, false, true><<<dim3(32, 32, 8), 256, 0, stream>>>(
        S_bf, K_bf, attn, nullptr, 0.08838834764831845f, 128, 1024, 1024, 4096,
        128, 128, 16777216, 0);
    // softmax over knowledge dim + post-softmax mask, in place
    softmax_mask<<<32768, 256, 0, stream>>>(attn, mask);
    // h = relu(sum_h attn_h @ V_h + b1)  : M=4096,N=1024,K=32768, A fp32 from d_out
    gemm_nt<true, true, false><<<dim3(8, 32, 1), 256, 0, stream>>>(
        attn, V_T, h_bf, b1, 1.0f, 32768, 4096, 32768, 1024, 0, 0, 0, 16777216 - 4096);
    // output = h @ W2 + b2 -> d_out[0:4M] fp32
    gemm_nt<false, false, true><<<dim3(8, 32, 1), 256, 0, stream>>>(
        h_bf, W2T, out, b2, 1.0f, 1024, 1024, 1024, 1024, 0, 0, 0, 0);
}

// Round 2
// 1700.992 us; speedup vs baseline: 1.2734x; 1.2734x over previous
//
#include <hip/hip_runtime.h>
#include <hip/hip_bf16.h>

typedef __attribute__((ext_vector_type(4))) float  floatx4;
typedef __attribute__((ext_vector_type(8))) short  shortx8;
typedef __attribute__((ext_vector_type(4))) short  shortx4;

__device__ __forceinline__ short f2bf(float x) {
    union { float f; unsigned u; } v; v.f = x;
    unsigned r = v.u + 0x7FFFu + ((v.u >> 16) & 1u);   // round-to-nearest-even
    return (short)(r >> 16);
}
__device__ __forceinline__ float bf2f(short x) {
    union { unsigned u; float f; } c; c.u = ((unsigned)(unsigned short)x) << 16;
    return c.f;
}

// ---------------- prep kernels ----------------

__global__ void cast_bf16(const float* __restrict__ src, short* __restrict__ dst, int n4) {
    int i = blockIdx.x * blockDim.x + threadIdx.x;
    if (i < n4) {
        floatx4 v = ((const floatx4*)src)[i];
        shortx4 s;
        s[0] = f2bf(v[0]); s[1] = f2bf(v[1]); s[2] = f2bf(v[2]); s[3] = f2bf(v[3]);
        ((shortx4*)dst)[i] = s;
    }
}

// dst[c][r] = (bf16)src[r][c], per-z batch. src: R x C fp32. dst: C x R bf16.
__global__ void transpose_cast(const float* __restrict__ src, short* __restrict__ dst,
                               int R, int C, long szSrc, long szDst) {
    __shared__ float tile[32][33];
    const float* s = src + (long)blockIdx.z * szSrc;
    short* d = dst + (long)blockIdx.z * szDst;
    int c0 = blockIdx.x * 32, r0 = blockIdx.y * 32;
    for (int i = threadIdx.y; i < 32; i += 8)
        tile[i][threadIdx.x] = s[(long)(r0 + i) * C + c0 + threadIdx.x];
    __syncthreads();
    for (int i = threadIdx.y; i < 32; i += 8)
        d[(long)(c0 + i) * R + r0 + threadIdx.x] = f2bf(tile[threadIdx.x][i]);
}

// ---------------- NT GEMM: C[M,N] = A[M,K] * B[N,K]^T ----------------
// 128x128 tile, BK=32, 256 threads = 4 waves (2x2), each wave 4x4 mfma 16x16x32.
// LDS row stride padded 32->40 shorts (80 B): bank = (row*20+quad*4)%32, only
// 2-way aliasing (free per m136) instead of 8-way at stride 64 B.
// aHX: extra element offset added per 4096 of block-local k (per-head attn layout).

#define BM 128
#define BN 128
#define BK 32
#define LSTR 40   // LDS row stride in shorts

template<bool AF32, bool RELU, bool CF32>
__global__ __launch_bounds__(256) void gemm_nt(
    const void* __restrict__ Ap, const short* __restrict__ Bp, void* __restrict__ Cp,
    const float* __restrict__ bias, float alpha,
    int K, int lda, int ldb, int ldc,
    long sAz, long sBz, long sCz, long aHX, long sbias)
{
    __shared__ __align__(16) short As[BM * LSTR];
    __shared__ __align__(16) short Bs[BN * LSTR];

    const int t    = threadIdx.x;
    const int m0   = blockIdx.y * BM;
    const int n0   = blockIdx.x * BN;
    const int z    = blockIdx.z;
    const int wave = t >> 6, lane = t & 63;
    const int wm   = (wave & 1) * 64, wn = (wave >> 1) * 64;
    const int quad = lane >> 4, l16 = lane & 15;

    const short* Bz = Bp + (long)z * sBz;

    floatx4 acc[4][4] = {};

    for (int k0 = 0; k0 < K; k0 += BK) {
        const long hoff = (long)(k0 >> 12) * aHX;
        __syncthreads();
        if (AF32) {
            const float* Az = (const float*)Ap + (long)z * sAz + hoff;
            #pragma unroll
            for (int p = 0; p < 4; ++p) {
                int idx = (p * 256 + t) * 4;
                int row = idx >> 5, kk = idx & 31;
                floatx4 v = *(const floatx4*)(Az + (long)(m0 + row) * lda + (k0 + kk));
                shortx4 sv;
                sv[0] = f2bf(v[0]); sv[1] = f2bf(v[1]); sv[2] = f2bf(v[2]); sv[3] = f2bf(v[3]);
                *(shortx4*)(&As[row * LSTR + kk]) = sv;
            }
        } else {
            const short* Az = (const short*)Ap + (long)z * sAz + hoff;
            #pragma unroll
            for (int p = 0; p < 2; ++p) {
                int idx = (p * 256 + t) * 8;
                int row = idx >> 5, kk = idx & 31;
                *(shortx8*)(&As[row * LSTR + kk]) =
                    *(const shortx8*)(Az + (long)(m0 + row) * lda + (k0 + kk));
            }
        }
        #pragma unroll
        for (int p = 0; p < 2; ++p) {
            int idx = (p * 256 + t) * 8;
            int row = idx >> 5, kk = idx & 31;
            *(shortx8*)(&Bs[row * LSTR + kk]) =
                *(const shortx8*)(Bz + (long)(n0 + row) * ldb + (k0 + kk));
        }
        __syncthreads();

        shortx8 af[4], bfr[4];
        #pragma unroll
        for (int i = 0; i < 4; ++i)
            af[i] = *(const shortx8*)(&As[(wm + i * 16 + l16) * LSTR + quad * 8]);
        #pragma unroll
        for (int j = 0; j < 4; ++j)
            bfr[j] = *(const shortx8*)(&Bs[(wn + j * 16 + l16) * LSTR + quad * 8]);
        #pragma unroll
        for (int i = 0; i < 4; ++i)
            #pragma unroll
            for (int j = 0; j < 4; ++j)
                acc[i][j] = __builtin_amdgcn_mfma_f32_16x16x32_bf16(af[i], bfr[j], acc[i][j], 0, 0, 0);
    }

    // epilogue: C/D layout col=lane&15, row=quad*4+e (m89-verified)
    float bv[4];
    #pragma unroll
    for (int j = 0; j < 4; ++j)
        bv[j] = bias ? (bias + (long)z * sbias)[n0 + wn + j * 16 + l16] : 0.0f;

    #pragma unroll
    for (int i = 0; i < 4; ++i) {
        #pragma unroll
        for (int e = 0; e < 4; ++e) {
            long row = m0 + wm + i * 16 + quad * 4 + e;
            #pragma unroll
            for (int j = 0; j < 4; ++j) {
                float val = acc[i][j][e] * alpha + bv[j];
                if (RELU) val = fmaxf(val, 0.0f);
                long col = n0 + wn + j * 16 + l16;
                if (CF32) ((float*)Cp + (long)z * sCz)[row * ldc + col] = val;
                else      ((short*)Cp + (long)z * sCz)[row * ldc + col] = f2bf(val);
            }
        }
    }
}

// ---------------- softmax(row) * mask, in place on fp32 scores ----------------

__global__ __launch_bounds__(256) void softmax_mask(float* __restrict__ attn,
                                                    const float* __restrict__ mask) {
    float* p = attn + (long)blockIdx.x * 4096;
    const int t = threadIdx.x;
    float v[16];
    float mx = -3.4e38f;
    #pragma unroll
    for (int i = 0; i < 16; ++i) { v[i] = p[t + 256 * i]; mx = fmaxf(mx, v[i]); }
    #pragma unroll
    for (int o = 32; o > 0; o >>= 1) mx = fmaxf(mx, __shfl_down(mx, o));
    __shared__ float r1[4], r2[4];
    const int lane = t & 63, w = t >> 6;
    if (lane == 0) r1[w] = mx;
    __syncthreads();
    mx = fmaxf(fmaxf(r1[0], r1[1]), fmaxf(r1[2], r1[3]));
    float s = 0.f;
    #pragma unroll
    for (int i = 0; i < 16; ++i) { v[i] = __expf(v[i] - mx); s += v[i]; }
    #pragma unroll
    for (int o = 32; o > 0; o >>= 1) s += __shfl_down(s, o);
    if (lane == 0) r2[w] = s;
    __syncthreads();
    s = r2[0] + r2[1] + r2[2] + r2[3];
    const float inv = 1.0f / s;
    #pragma unroll
    for (int i = 0; i < 16; ++i) p[t + 256 * i] = v[i] * inv * mask[t + 256 * i];
}

// ---------------- reduce split-K partials: h = relu(sum_z part_z + b1) -> bf16 ----

__global__ __launch_bounds__(256) void reduce_heads(const short* __restrict__ part,
                                                    const float* __restrict__ b1,
                                                    short* __restrict__ h_bf) {
    int i = blockIdx.x * blockDim.x + threadIdx.x;   // vec8 index over 4M elems
    float s[8] = {0,0,0,0,0,0,0,0};
    #pragma unroll
    for (int z = 0; z < 4; ++z) {
        shortx8 v = ((const shortx8*)(part + (long)z * 4194304))[i];
        #pragma unroll
        for (int e = 0; e < 8; ++e) s[e] += bf2f(v[e]);
    }
    int j0 = (i * 8) & 1023;
    shortx8 o;
    #pragma unroll
    for (int e = 0; e < 8; ++e) o[e] = f2bf(fmaxf(s[e] + b1[j0 + e], 0.f));
    ((shortx8*)h_bf)[i] = o;
}

// ---------------- launch ----------------

extern "C" void kernel_launch(void* const* d_in, const int* in_sizes, int n_in,
                              void* d_out, int out_size, void* d_ws, size_t ws_size,
                              hipStream_t stream) {
    const float* sentences = (const float*)d_in[0];
    const float* knowledge = (const float*)d_in[1];
    const float* mask      = (const float*)d_in[2];
    const float* Ws        = (const float*)d_in[3];
    const float* bs        = (const float*)d_in[4];
    const float* Wk        = (const float*)d_in[5];
    const float* bk        = (const float*)d_in[6];
    const float* W1        = (const float*)d_in[7];
    const float* b1        = (const float*)d_in[8];
    const float* W2        = (const float*)d_in[9];
    const float* b2        = (const float*)d_in[10];

    float* out  = (float*)d_out;
    float* attn = out + 4194304;           // weights region: [8*4096, 4096] fp32

    // ws layout (total ~126 MB, <= round-1's working 132 MB):
    //   [0,64M)       V_T      (live: V GEMM -> big GEMM)
    //   [64M,66M)     W2T      (live to end)
    //   [66M,74M)     h_bf     (live: reduce -> final GEMM)
    //   [74M,+16K)    bias2    (bs||bk for batched projection)
    //   pool [77611008, ...):  prep/intermediate buffers, all dead before the
    //                          big GEMM; partials (32 MB bf16) alias pool start.
    char* ws = (char*)d_ws;
    short* V_T     = (short*)(ws);                   // 64 MB  [j][h*4096+m]
    short* W2T     = (short*)(ws + 67108864);        //  2 MB  [j2][j]
    short* h_bf    = (short*)(ws + 69206016);        //  8 MB  [n][j]
    float* bias2   = (float*)(ws + 77594624);        // 16 KB  bs||bk
    short* sent_bf = (short*)(ws + 77611008);        //  8 MB
    short* know_bf = (short*)(ws + 85999616);        //  8 MB
    short* WsT     = (short*)(ws + 94388224);        //  2 MB  [j=h*128+e][d]
    short* WkT     = (short*)(ws + 96485376);        //  2 MB
    short* W1T     = (short*)(ws + 98582528);        // 16 MB  [h][j][d]
    short* S_bf    = (short*)(ws + 115359744);       //  8 MB  [n][h*128+e]
    short* K_bf    = (short*)(ws + 123748352);       //  8 MB  [m][h*128+e]
    short* part    = (short*)(ws + 77611008);        // 32 MB bf16, aliases dead pool

    // prep: casts + weight transposes + bias pack
    cast_bf16<<<4096, 256, 0, stream>>>(sentences, sent_bf, 1048576);
    cast_bf16<<<4096, 256, 0, stream>>>(knowledge, know_bf, 1048576);
    transpose_cast<<<dim3(4, 32, 8),  dim3(32, 8), 0, stream>>>(Ws, WsT, 1024, 128, 131072, 131072);
    transpose_cast<<<dim3(4, 32, 8),  dim3(32, 8), 0, stream>>>(Wk, WkT, 1024, 128, 131072, 131072);
    transpose_cast<<<dim3(32, 32, 8), dim3(32, 8), 0, stream>>>(W1, W1T, 1024, 1024, 1048576, 1048576);
    transpose_cast<<<dim3(32, 32, 1), dim3(32, 8), 0, stream>>>(W2, W2T, 1024, 1024, 0, 0);
    hipMemcpyAsync(bias2,        bs, 4096, hipMemcpyDeviceToDevice, stream);
    hipMemcpyAsync(bias2 + 1024, bk, 4096, hipMemcpyDeviceToDevice, stream);

    // batched S/K projection: z=0 sentences@Ws+bs, z=1 knowledge@Wk+bk
    gemm_nt<false, false, false><<<dim3(8, 32, 2), 256, 0, stream>>>(
        sent_bf, WsT, S_bf, bias2, 1.0f, 1024, 1024, 1024, 1024,
        4194304, 1048576, 4194304, 0, 1024);
    // V_T[j][h*4096+m] = (knowledge @ W1_h)[m][j]
    gemm_nt<false, false, false><<<dim3(32, 8, 8), 256, 0, stream>>>(
        W1T, know_bf, V_T, nullptr, 1.0f, 1024, 1024, 1024, 32768,
        1048576, 0, 4096, 0, 0);
    // raw scores -> d_out weights region (fp32), scaled 1/sqrt(128)
    gemm_nt<false, false, true><<<dim3(32, 32, 8), 256, 0, stream>>>(
        S_bf, K_bf, attn, nullptr, 0.08838834764831845f, 128, 1024, 1024, 4096,
        128, 128, 16777216, 0, 0);
    // softmax over knowledge dim + post-softmax mask, in place
    softmax_mask<<<32768, 256, 0, stream>>>(attn, mask);
    // big GEMM, split-K over head pairs: part[z] = attn[:, z-pair] @ V_T[z-pair]^T
    // z in [0,4): heads 2z,2z+1; K=8192; A fp32 from d_out
    gemm_nt<true, false, false><<<dim3(8, 32, 4), 256, 0, stream>>>(
        attn, V_T, part, nullptr, 1.0f, 8192, 4096, 32768, 1024,
        33554432, 8192, 4194304, 16777216 - 4096, 0);
    // h = relu(sum_z part_z + b1) -> bf16
    reduce_heads<<<2048, 256, 0, stream>>>(part, b1, h_bf);
    // output = h @ W2 + b2 -> d_out[0:4M] fp32
    gemm_nt<false, false, true><<<dim3(8, 32, 1), 256, 0, stream>>>(
        h_bf, W2T, out, b2, 1.0f, 1024, 1024, 1024, 1024, 0, 0, 0, 0, 0);
}